// Round 6
// baseline (183.804 us; speedup 1.0000x reference)
//
#include <hip/hip_runtime.h>

typedef __bf16 bf16x8 __attribute__((ext_vector_type(8)));
typedef float f32x4 __attribute__((ext_vector_type(4)));
typedef unsigned int uint4v __attribute__((ext_vector_type(4)));
typedef unsigned short ushort_t;
typedef unsigned int uint_t;

#define RS 0.08838834764831845f   // 1/sqrt(128)

__device__ __forceinline__ ushort_t f2bf(float f) {
    uint_t u = __float_as_uint(f);
    u += 0x7FFFu + ((u >> 16) & 1u);   // round-to-nearest-even
    return (ushort_t)(u >> 16);
}
__device__ __forceinline__ uint_t pack2(float a, float b) {
    return (uint_t)f2bf(a) | ((uint_t)f2bf(b) << 16);
}
union U4B8 { uint4v u; bf16x8 b; };
__device__ __forceinline__ bf16x8 as_bf(uint4v u) { U4B8 x; x.u = u; return x.b; }

// padded xs frag addressing: frag stride 1072B (67x16), phase stride 272B (17x16)
__device__ __forceinline__ int xfrag(int f, int lane) {
    return f * 1072 + ((lane >> 4) * 272) + ((lane & 15) * 16);
}

// async global->LDS, 16B/lane; LDS dest = wave-uniform base + lane*16 (m104)
__device__ __forceinline__ void gload16(const void* g, void* l) {
    __builtin_amdgcn_global_load_lds(
        (const __attribute__((address_space(1))) void*)g,
        (__attribute__((address_space(3))) void*)l, 16, 0, 0);
}

// ---------------------------------------------------------------------------
// Prep (one dispatch, 576 blocks) — R11-proven, verbatim. Blocks 0..63:
// K'[m]=keys[m]@Wq + cb[m]=bq.keys[m]. Blocks 64..575: swizzle ops -> bf16
// B-frag order, each (m,dh) half-tile contiguous (16 KB):
//   h = m*2048 + (dt>>2)*1024 + ks*256 + (dt&3)*64 + L
// ---------------------------------------------------------------------------
__global__ __launch_bounds__(256) void prep_kernel(
    const float* __restrict__ ops, const float* __restrict__ keys,
    const float* __restrict__ Wq, const float* __restrict__ bq,
    uint4v* __restrict__ ops_sw, ushort_t* __restrict__ kp_sw,
    float* __restrict__ cb)
{
    const int tid = threadIdx.x;
    const int b = blockIdx.x;
    if (b >= 64) {
        int g = (b - 64) * 256 + tid;     // [0, 131072)
        int L = g & 63, dt = (g >> 6) & 7, ks = (g >> 9) & 3, m = g >> 11;
        int d = dt * 16 + (L & 15);
        int e0 = ks * 32 + ((L >> 4) << 3);
        const float4* s = (const float4*)(ops + (((size_t)(m * 128 + d)) << 7) + e0);
        float4 v0 = s[0], v1 = s[1];
        uint4v o = { pack2(v0.x, v0.y), pack2(v0.z, v0.w),
                     pack2(v1.x, v1.y), pack2(v1.z, v1.w) };
        int h = m * 2048 + (dt >> 2) * 1024 + ks * 256 + (dt & 3) * 64 + L;
        ops_sw[h] = o;
    } else {
        __shared__ float red[256];
        const int m = b;
        const int d = tid & 127, eh = tid >> 7;
        const float* kr = keys + m * 128 + eh * 64;
        const float* wc = Wq + (size_t)(eh * 64) * 128 + d;
        float acc = 0.f;
        #pragma unroll 8
        for (int e = 0; e < 64; ++e)
            acc = fmaf(kr[e], wc[(size_t)e * 128], acc);
        red[tid] = acc;
        __syncthreads();
        if (tid < 128) {
            float v = red[tid] + red[tid + 128];
            int ki = d >> 5, qq = (d >> 3) & 3, j = d & 7;
            kp_sw[((((ki * 4 + (m >> 4)) * 64) + (qq * 16 + (m & 15))) << 3) | j] = f2bf(v);
        } else if (tid >= 192) {
            int lane = tid - 192;
            float p = keys[m * 128 + lane] * bq[lane]
                    + keys[m * 128 + 64 + lane] * bq[64 + lane];
            #pragma unroll
            for (int off = 1; off < 64; off <<= 1) p += __shfl_xor(p, off);
            if (lane == 0) cb[m] = p;
        }
    }
}

// ---------------------------------------------------------------------------
// Main: 256 blocks (1/CU), 512 threads (8 waves). Block = 128t x 64d x all 64
// slots; wave = (slh=w&1 slot parity, dtp=w>>1 d-16-tile) per R14's remap.
// R15: BARRIER-FREE self-paced loop. Since R14, each wave's B-slice is
// consumed ONLY by that wave -> the per-pair s_barrier (the m233 "2-phase
// stall": 8-wave lockstep reconvergence 32x) protects nothing. Ring becomes
// wave-private ([slot][wave] 4KB regions, depth 3 = 96KB). Per iter p:
//   wait vmcnt(8)          (own stage(p) landed; stages p+1,p+2 in flight)
//   ds_read own 4 B-frags  (slot p%3)
//   lgkmcnt(0)+sched_barrier(0)   (WAR fence, rule #18)
//   issue own stage(p+3) into just-freed slot p%3
//   32 MFMA + 8 attn-FMA
// No s_barrier in the loop. Waves drift; 2 waves/SIMD fill each other's
// dependency stalls (m114); stage latency hides under own-MFMA slack.
// LDS: [0,98304) ring 3 x [8w x 4KB]; [98304,131072) attn XOR-swz [64][128];
// xs (34304B) at [64000,98304) aliases slot1-tail/slot2 -> stage(1)/(2)
// issued only after xs is dead; pre-phase-2 stage(0) targets slot0, disjoint.
// ---------------------------------------------------------------------------
__global__ __launch_bounds__(512, 2) void main_kernel(
    const float* __restrict__ x, const float* __restrict__ cb,
    const ushort_t* __restrict__ kp_sw, const uint4v* __restrict__ ops_sw,
    float* __restrict__ out)
{
    __shared__ __align__(16) unsigned char lds[131072];
    uint4v* bb = (uint4v*)lds;                    // 3 slots x 8 waves x 4KB
    unsigned char* xs = lds + 64000;              // 34304B, dead pre-stage(1)
    float* attn_f = (float*)(lds + 98304);        // [m][t ^ ((m&7)<<2)]

    const int tid = threadIdx.x;          // 0..511
    const int lane = tid & 63;
    const int w = tid >> 6;               // wave 0..7
    const int q = lane >> 4;
    const int l15 = lane & 15;
    const int tb = blockIdx.x >> 1;       // token tile 0..127
    const int dh = blockIdx.x & 1;
    const int t0 = tb * 128;
    const int slh = w & 1;                // slot parity
    const int dtp = w >> 1;               // d-16-tile within half

    // wave-private stage: my 4KB B-slice (slot m=2*pair+slh, my dtp) -> ring s
    auto stage = [&](int pair, int s) {
        const int m = pair * 2 + slh;
        uint4v* dst = bb + s * 2048 + w * 256;                    // uniform base
        const uint4v* src = ops_sw + (size_t)m * 2048 + dh * 1024
                          + dtp * 64 + lane;                      // per-lane
        #pragma unroll
        for (int ks = 0; ks < 4; ++ks)
            gload16((const void*)(src + ks * 256), (void*)(dst + ks * 64));
    };

    // ---- Phase 1: stage x tile (128x128) -> bf16 A-frag order (xs, padded)
    {
        const float4* x4 = (const float4*)(x + (size_t)t0 * 128);
        #pragma unroll
        for (int it = 0; it < 4; ++it) {
            int i = it * 512 + tid;
            int t = i >> 4, kc = i & 15;
            float4 a = x4[t * 32 + kc * 2];
            float4 b2 = x4[t * 32 + kc * 2 + 1];
            uint4v o = { pack2(a.x, a.y), pack2(a.z, a.w),
                         pack2(b2.x, b2.y), pack2(b2.z, b2.w) };
            *(uint4v*)(xs + ((t >> 4) * 4 + (kc >> 2)) * 1072
                          + (kc & 3) * 272 + (t & 15) * 16) = o;
        }
    }
    __syncthreads();

    // Pair-0 stage (slot 0, disjoint from xs/attn): hides under phase 2.
    stage(0, 0);

    // ---- Phase 2: attention (wave w owns tokens w*16..w*16+15), all 64 slots
    {
        f32x4 L0 = {0,0,0,0}, L1 = {0,0,0,0}, L2 = {0,0,0,0}, L3 = {0,0,0,0};
        const uint4v* kpf = (const uint4v*)kp_sw;
        #pragma unroll
        for (int ki = 0; ki < 4; ++ki) {
            bf16x8 a = *(const bf16x8*)(xs + xfrag(w * 4 + ki, lane));
            L0 = __builtin_amdgcn_mfma_f32_16x16x32_bf16(a, as_bf(kpf[(ki*4+0)*64 + lane]), L0, 0,0,0);
            L1 = __builtin_amdgcn_mfma_f32_16x16x32_bf16(a, as_bf(kpf[(ki*4+1)*64 + lane]), L1, 0,0,0);
            L2 = __builtin_amdgcn_mfma_f32_16x16x32_bf16(a, as_bf(kpf[(ki*4+2)*64 + lane]), L2, 0,0,0);
            L3 = __builtin_amdgcn_mfma_f32_16x16x32_bf16(a, as_bf(kpf[(ki*4+3)*64 + lane]), L3, 0,0,0);
        }
        float c0 = cb[l15], c1 = cb[16 + l15], c2 = cb[32 + l15], c3 = cb[48 + l15];
        #pragma unroll
        for (int r = 0; r < 4; ++r) {
            float v0 = (L0[r] + c0) * RS;
            float v1 = (L1[r] + c1) * RS;
            float v2 = (L2[r] + c2) * RS;
            float v3 = (L3[r] + c3) * RS;
            float mx = fmaxf(fmaxf(v0, v1), fmaxf(v2, v3));
            #pragma unroll
            for (int off = 1; off < 16; off <<= 1) mx = fmaxf(mx, __shfl_xor(mx, off));
            float e0 = __expf(v0 - mx), e1 = __expf(v1 - mx),
                  e2 = __expf(v2 - mx), e3 = __expf(v3 - mx);
            float sm = e0 + e1 + e2 + e3;
            #pragma unroll
            for (int off = 1; off < 16; off <<= 1) sm += __shfl_xor(sm, off);
            float inv = 1.0f / sm;
            int t = w * 16 + q * 4 + r;
            int ts = t ^ ((l15 & 7) << 2);   // XOR bank-swizzle (bits 2..4)
            attn_f[(     l15) * 128 + ts] = e0 * inv;
            attn_f[(16 + l15) * 128 + ts] = e1 * inv;
            attn_f[(32 + l15) * 128 + ts] = e2 * inv;
            attn_f[(48 + l15) * 128 + ts] = e3 * inv;
        }
    }

    // ---- A-frags for ALL 8 token-16-groups (wave MFMAs every token)
    bf16x8 A[8][4];
    #pragma unroll
    for (int tf = 0; tf < 8; ++tf)
        #pragma unroll
        for (int ki = 0; ki < 4; ++ki)
            A[tf][ki] = *(const bf16x8*)(xs + xfrag(tf * 4 + ki, lane));

    // attn published + xs dead everywhere. (Drains stage(0) — it landed
    // during phase 2 anyway; vmcnt==0 baseline for the counted loop.)
    __syncthreads();

    // Now xs is dead: safe to stage into slots 1,2 (alias xs region).
    stage(1, 1);
    stage(2, 2);

    f32x4 C[8] = {};   // partial sums over this wave's slot parity

    auto computeSlot = [&](int p, int s, bool doStage) {
        const int m = 2 * p + slh;
        const int msw = (m & 7) << 2;
        bf16x8 Bf[4];
        #pragma unroll
        for (int ki = 0; ki < 4; ++ki)
            Bf[ki] = as_bf(bb[s * 2048 + w * 256 + ki * 64 + lane]);
        // WAR fence: my B reads complete before I overwrite slot s (rule #18)
        asm volatile("s_waitcnt lgkmcnt(0)" ::: "memory");
        __builtin_amdgcn_sched_barrier(0);
        if (doStage) stage(p + 3, s);
        #pragma unroll
        for (int th = 0; th < 2; ++th) {
            f32x4 S[4] = {};
            __builtin_amdgcn_s_setprio(1);
            #pragma unroll
            for (int ki = 0; ki < 4; ++ki)
                #pragma unroll
                for (int tf = 0; tf < 4; ++tf)
                    S[tf] = __builtin_amdgcn_mfma_f32_16x16x32_bf16(
                        A[th * 4 + tf][ki], Bf[ki], S[tf], 0, 0, 0);
            __builtin_amdgcn_s_setprio(0);
            #pragma unroll
            for (int tf = 0; tf < 4; ++tf) {
                int ta = ((th * 4 + tf) * 16 + q * 4) ^ msw;
                f32x4 af = *(const f32x4*)&attn_f[m * 128 + ta];
                #pragma unroll
                for (int r = 0; r < 4; ++r)
                    C[th * 4 + tf][r] = fmaf(af[r], S[tf][r], C[th * 4 + tf][r]);
            }
        }
    };

    // ---- Phase 3: 32 slots/wave, barrier-free counted-vmcnt pipeline.
    // Outstanding stages at each wait: p+1, p+2 (+ p+3 after prior issue)
    // -> vmcnt(8) guarantees stage(p) landed. Tail peels to 4 then 0.
    #pragma unroll 3
    for (int p = 0; p < 30; ++p) {
        asm volatile("s_waitcnt vmcnt(8)" ::: "memory");
        computeSlot(p, p % 3, p < 29);
    }
    asm volatile("s_waitcnt vmcnt(4)" ::: "memory");
    computeSlot(30, 0, false);
    asm volatile("s_waitcnt vmcnt(0)" ::: "memory");
    computeSlot(31, 1, false);

    // ---- Epilogue: cross-parity reduction (attn buffer dead -> reuse),
    // then direct stores by even-parity waves.
    __syncthreads();
    f32x4* rb = (f32x4*)(lds + 98304);   // 4 dtp x 8 tf x 64 lanes = 32 KB
    if (slh == 1) {
        #pragma unroll
        for (int tf = 0; tf < 8; ++tf)
            rb[dtp * 512 + tf * 64 + lane] = C[tf];
    }
    __syncthreads();
    if (slh == 0) {
        float* op = out + (size_t)t0 * 128 + dh * 64 + dtp * 16 + l15;
        #pragma unroll
        for (int tf = 0; tf < 8; ++tf) {
            f32x4 other = rb[dtp * 512 + tf * 64 + lane];
            #pragma unroll
            for (int r = 0; r < 4; ++r)
                op[(size_t)(tf * 16 + q * 4 + r) * 128] = C[tf][r] + other[r];
        }
    }
}

// ---------------------------------------------------------------------------
extern "C" void kernel_launch(void* const* d_in, const int* in_sizes, int n_in,
                              void* d_out, int out_size, void* d_ws, size_t ws_size,
                              hipStream_t stream)
{
    const float* x    = (const float*)d_in[0];   // (4,4096,128)
    const float* keys = (const float*)d_in[1];   // (64,128)
    const float* ops  = (const float*)d_in[2];   // (64,128,128)
    const float* Wq   = (const float*)d_in[3];   // (128,128)
    const float* bq   = (const float*)d_in[4];   // (128,)
    float* out = (float*)d_out;

    char* ws = (char*)d_ws;
    uint4v*   ops_sw = (uint4v*)ws;                        // 2 MB
    ushort_t* kp_sw  = (ushort_t*)(ws + 2097152);          // 16 KB
    float*    cb     = (float*)(ws + 2097152 + 16384);     // 256 B

    prep_kernel<<<576, 256, 0, stream>>>(ops, keys, Wq, bq, ops_sw, kp_sw, cb);
    main_kernel<<<256, 512, 0, stream>>>(x, cb, kp_sw, ops_sw, out);
}

// Round 7
// 160.915 us; speedup vs baseline: 1.1422x; 1.1422x over previous
//
#include <hip/hip_runtime.h>

typedef __bf16 bf16x8 __attribute__((ext_vector_type(8)));
typedef float f32x4 __attribute__((ext_vector_type(4)));
typedef unsigned int uint4v __attribute__((ext_vector_type(4)));
typedef unsigned short ushort_t;
typedef unsigned int uint_t;

#define RS 0.08838834764831845f   // 1/sqrt(128)

__device__ __forceinline__ ushort_t f2bf(float f) {
    uint_t u = __float_as_uint(f);
    u += 0x7FFFu + ((u >> 16) & 1u);   // round-to-nearest-even
    return (ushort_t)(u >> 16);
}
__device__ __forceinline__ uint_t pack2(float a, float b) {
    return (uint_t)f2bf(a) | ((uint_t)f2bf(b) << 16);
}
union U4B8 { uint4v u; bf16x8 b; };
__device__ __forceinline__ bf16x8 as_bf(uint4v u) { U4B8 x; x.u = u; return x.b; }

// padded xs frag addressing: frag stride 1072B (67x16), phase stride 272B (17x16)
__device__ __forceinline__ int xfrag(int f, int lane) {
    return f * 1072 + ((lane >> 4) * 272) + ((lane & 15) * 16);
}

// ---------------------------------------------------------------------------
// R16: ONE dispatch, no workspace, no grid barrier (R12's failure mode).
// Each of 256 blocks (1/CU, 512 thr) is SELF-SUFFICIENT:
//   P0  stage keys(32KB)+Wq(64KB) f32 -> LDS (coalesced)
//   P1  K' = keys@Wq redundantly per block, exact f32 VALU (1M FMA / 512 thr
//       = 2048 FMA/thr ~3.4us, same numerics as old prep) -> kp frags + cb
//   P2  x-tile -> bf16 A-frag LDS (xs); issue pair-0 B loads (hide under P3)
//   P3  attention (kp/cb from LDS), A-frags -> regs
//   loop: R2-proven compute structure; B staged from f32 ops by per-lane
//       loads + in-reg bf16 pack + ds_write (per-lane src addr does the
//       swizzle that gload_lds couldn't), 3-buffer ring, one barrier/pair.
//       Loads for pair p+1 issue at iter-p TOP -> ~1500cy slack before their
//       vmcnt(0) drain at iter-p BOTTOM (fixes R10's 310cy-slack failure).
// LDS map (147712B):
//   [0,98304)       ring 3x32KB   (P0/P1 alias: keysL [0,32768) wqL [32768,98304))
//   [32768,67072)   xs 34304B     (alias ring buf1+buf2-head; dead pre-write(1))
//   [98304,114688)  kp ushort[8192]
//   [114688,147456) attn f32[64][128] (slot-XOR col swizzle)
//   [147456,147712) cb f32[64]
// WAR/RAW proof: buf0 written (write(0)) after P1 barrier (keysL dead);
// write(k) at iter k-1 bottom, read at iter k top, one barrier between; ring
// depth 3 => rewrite of buf b separated from its last reader by >=1 barrier.
// ---------------------------------------------------------------------------
__global__ __launch_bounds__(512, 2) void fused_kernel(
    const float* __restrict__ x, const float* __restrict__ keys,
    const float* __restrict__ ops, const float* __restrict__ Wq,
    const float* __restrict__ bq, float* __restrict__ out)
{
    __shared__ __align__(16) unsigned char lds[147712];
    uint4v* bb = (uint4v*)lds;                    // ring 3 x 2048 uint4v
    unsigned char* xs = lds + 32768;              // A-frag staging (alias)
    ushort_t* kpL = (ushort_t*)(lds + 98304);     // K' bf16 frags
    float* attn_f = (float*)(lds + 114688);       // [m][t ^ ((m&7)<<2)]
    float* cbL = (float*)(lds + 147456);          // bias.keys per slot

    const int tid = threadIdx.x;          // 0..511
    const int lane = tid & 63;
    const int w = tid >> 6;               // wave 0..7
    const int q = lane >> 4;
    const int l15 = lane & 15;
    const int tb = blockIdx.x >> 1;       // token tile 0..127
    const int dh = blockIdx.x & 1;
    const int t0 = tb * 128;
    const int dtp = w & 3;                // d-16-tile within half
    const int tg = w >> 2;                // token 64-group

    // ---- P0: stage keys + Wq (f32) into LDS, coalesced
    {
        float4* kd = (float4*)lds;
        const float4* ks4 = (const float4*)keys;
        #pragma unroll
        for (int i = 0; i < 4; ++i) kd[i * 512 + tid] = ks4[i * 512 + tid];
        float4* wd = (float4*)(lds + 32768);
        const float4* wq4 = (const float4*)Wq;
        #pragma unroll
        for (int i = 0; i < 8; ++i) wd[i * 512 + tid] = wq4[i * 512 + tid];
    }
    __syncthreads();

    // ---- P1: K'[m][d] = sum_e keys[m][e] * Wq[e][d]  (exact f32), + cb
    {
        const float* keysL = (const float*)lds;
        const float* wqL = (const float*)(lds + 32768);
        const int m = tid >> 3;            // 64 slots, 8 threads each
        const int d0 = (tid & 7) << 4;     // 16 output cols per thread
        float acc[16];
        #pragma unroll
        for (int j = 0; j < 16; ++j) acc[j] = 0.f;
        const float* kr = keysL + m * 128;
        const float* wr = wqL + d0;
        #pragma unroll 2
        for (int e = 0; e < 128; ++e) {
            float kv = kr[e];
            const f32x4* wv = (const f32x4*)(wr + (size_t)e * 128);
            #pragma unroll
            for (int jj = 0; jj < 4; ++jj) {
                f32x4 v = wv[jj];
                #pragma unroll
                for (int r = 0; r < 4; ++r)
                    acc[jj * 4 + r] = fmaf(kv, v[r], acc[jj * 4 + r]);
            }
        }
        // pack to kp frag layout: kp[((ki*4+(m>>4))*64 + qq*16 + (m&15))*8+j]
        const int ki = d0 >> 5;
        const int qq0 = (d0 >> 3) & 3;     // d0..d0+7 -> qq0; +8..15 -> qq0+1
        const int base0 = (((ki * 4 + (m >> 4)) * 64) + (qq0 * 16 + (m & 15))) << 3;
        const int base1 = (((ki * 4 + (m >> 4)) * 64) + ((qq0 + 1) * 16 + (m & 15))) << 3;
        uint4v k0 = { pack2(acc[0], acc[1]),  pack2(acc[2], acc[3]),
                      pack2(acc[4], acc[5]),  pack2(acc[6], acc[7]) };
        uint4v k1 = { pack2(acc[8], acc[9]),  pack2(acc[10], acc[11]),
                      pack2(acc[12], acc[13]), pack2(acc[14], acc[15]) };
        *(uint4v*)(kpL + base0) = k0;
        *(uint4v*)(kpL + base1) = k1;
        if (tid < 64) {
            float s = 0.f;
            const float* krow = keysL + tid * 128;
            #pragma unroll 4
            for (int e = 0; e < 128; ++e) s = fmaf(krow[e], bq[e], s);
            cbL[tid] = s;
        }
    }
    __syncthreads();   // keysL/wqL dead; kp + cb published

    // ---- reg-staging machinery: pair p = slots (2p, 2p+1), dh half, 64KB f32
    // thread stages 4 frags (f = w*4+j): sl=f>>4, ks=(f>>2)&3, dtl=f&3.
    float4 G[8];
    auto issueLoads = [&](int p) {
        #pragma unroll
        for (int j = 0; j < 4; ++j) {
            const int f = w * 4 + j;
            const int sl = f >> 4, ks = (f >> 2) & 3, dtl = f & 3;
            const float* src = ops + (size_t)(2 * p + sl) * 16384
                             + (size_t)(dh * 64 + dtl * 16 + l15) * 128
                             + ks * 32 + (q << 3);
            G[j * 2]     = *(const float4*)src;
            G[j * 2 + 1] = *(const float4*)(src + 4);
        }
    };
    auto packWrite = [&](int b) {
        #pragma unroll
        for (int j = 0; j < 4; ++j) {
            const int f = w * 4 + j;
            const int sl = f >> 4, ks = (f >> 2) & 3, dtl = f & 3;
            float4 v0 = G[j * 2], v1 = G[j * 2 + 1];
            uint4v o = { pack2(v0.x, v0.y), pack2(v0.z, v0.w),
                         pack2(v1.x, v1.y), pack2(v1.z, v1.w) };
            bb[b * 2048 + sl * 1024 + ks * 256 + dtl * 64 + lane] = o;
        }
    };

    // issue pair-0 loads now: latency hides under P2+P3 (~3us of compute)
    issueLoads(0);

    // ---- P2: x tile (128x128) -> bf16 A-frag order (xs)
    {
        const float4* x4 = (const float4*)(x + (size_t)t0 * 128);
        #pragma unroll
        for (int it = 0; it < 4; ++it) {
            int i = it * 512 + tid;
            int t = i >> 4, kc = i & 15;
            float4 a = x4[t * 32 + kc * 2];
            float4 b2 = x4[t * 32 + kc * 2 + 1];
            uint4v o = { pack2(a.x, a.y), pack2(a.z, a.w),
                         pack2(b2.x, b2.y), pack2(b2.z, b2.w) };
            *(uint4v*)(xs + ((t >> 4) * 4 + (kc >> 2)) * 1072
                          + (kc & 3) * 272 + (t & 15) * 16) = o;
        }
    }
    __syncthreads();

    // ---- P3: attention (wave w owns tokens w*16..w*16+15), all 64 slots
    {
        f32x4 L0 = {0,0,0,0}, L1 = {0,0,0,0}, L2 = {0,0,0,0}, L3 = {0,0,0,0};
        const uint4v* kpf = (const uint4v*)kpL;
        #pragma unroll
        for (int ki = 0; ki < 4; ++ki) {
            bf16x8 a = *(const bf16x8*)(xs + xfrag(w * 4 + ki, lane));
            L0 = __builtin_amdgcn_mfma_f32_16x16x32_bf16(a, as_bf(kpf[(ki*4+0)*64 + lane]), L0, 0,0,0);
            L1 = __builtin_amdgcn_mfma_f32_16x16x32_bf16(a, as_bf(kpf[(ki*4+1)*64 + lane]), L1, 0,0,0);
            L2 = __builtin_amdgcn_mfma_f32_16x16x32_bf16(a, as_bf(kpf[(ki*4+2)*64 + lane]), L2, 0,0,0);
            L3 = __builtin_amdgcn_mfma_f32_16x16x32_bf16(a, as_bf(kpf[(ki*4+3)*64 + lane]), L3, 0,0,0);
        }
        float c0 = cbL[l15], c1 = cbL[16 + l15], c2 = cbL[32 + l15], c3 = cbL[48 + l15];
        #pragma unroll
        for (int r = 0; r < 4; ++r) {
            float v0 = (L0[r] + c0) * RS;
            float v1 = (L1[r] + c1) * RS;
            float v2 = (L2[r] + c2) * RS;
            float v3 = (L3[r] + c3) * RS;
            float mx = fmaxf(fmaxf(v0, v1), fmaxf(v2, v3));
            #pragma unroll
            for (int off = 1; off < 16; off <<= 1) mx = fmaxf(mx, __shfl_xor(mx, off));
            float e0 = __expf(v0 - mx), e1 = __expf(v1 - mx),
                  e2 = __expf(v2 - mx), e3 = __expf(v3 - mx);
            float sm = e0 + e1 + e2 + e3;
            #pragma unroll
            for (int off = 1; off < 16; off <<= 1) sm += __shfl_xor(sm, off);
            float inv = 1.0f / sm;
            int t = w * 16 + q * 4 + r;
            int ts = t ^ ((l15 & 7) << 2);   // XOR bank-swizzle (bits 2..4)
            attn_f[(     l15) * 128 + ts] = e0 * inv;
            attn_f[(16 + l15) * 128 + ts] = e1 * inv;
            attn_f[(32 + l15) * 128 + ts] = e2 * inv;
            attn_f[(48 + l15) * 128 + ts] = e3 * inv;
        }
    }

    // ---- A-frags for this wave's 64-token group, kept all slot-loop
    bf16x8 A[4][4];
    #pragma unroll
    for (int tf = 0; tf < 4; ++tf)
        #pragma unroll
        for (int ki = 0; ki < 4; ++ki)
            A[tf][ki] = *(const bf16x8*)(xs + xfrag(tg * 16 + tf * 4 + ki, lane));

    __syncthreads();   // xs dead in ALL waves; attn published

    f32x4 C[4] = {};

    auto computePair = [&](int p) {
        const uint4v* bbuf = bb + (p % 3) * 2048 + dtp * 64 + lane;
        #pragma unroll
        for (int sl = 0; sl < 2; ++sl) {
            const int m = p * 2 + sl;
            const int msw = (m & 7) << 2;
            f32x4 S[4] = {};
            __builtin_amdgcn_s_setprio(1);
            #pragma unroll
            for (int ki = 0; ki < 4; ++ki) {
                bf16x8 bfrag = as_bf(bbuf[sl * 1024 + ki * 256]);
                #pragma unroll
                for (int tf = 0; tf < 4; ++tf)
                    S[tf] = __builtin_amdgcn_mfma_f32_16x16x32_bf16(A[tf][ki], bfrag, S[tf], 0,0,0);
            }
            __builtin_amdgcn_s_setprio(0);
            #pragma unroll
            for (int tf = 0; tf < 4; ++tf) {
                int ta = (tg * 64 + tf * 16 + q * 4) ^ msw;
                f32x4 af = *(const f32x4*)&attn_f[m * 128 + ta];
                #pragma unroll
                for (int r = 0; r < 4; ++r)
                    C[tf][r] = fmaf(af[r], S[tf][r], C[tf][r]);
            }
        }
    };

    // ---- prime: pair-0 loads -> buf0 (buf0 = dead keysL region)
    asm volatile("s_waitcnt vmcnt(0)" ::: "memory");
    packWrite(0);
    __syncthreads();

    // ---- Phase 4: 32 slot-pairs. Loads(p+1) issue at top (~1500cy slack),
    // drain + pack + write at bottom, one barrier per pair.
    for (int p = 0; p < 32; ++p) {
        if (p < 31) issueLoads(p + 1);
        computePair(p);
        if (p < 31) {
            asm volatile("s_waitcnt vmcnt(0)" ::: "memory");
            packWrite((p + 1) % 3);
            __syncthreads();
        }
    }

    // ---- Epilogue: direct stores (complete sums; no atomics)
    float* op = out + (size_t)t0 * 128 + dh * 64 + dtp * 16 + l15;
    #pragma unroll
    for (int tf = 0; tf < 4; ++tf)
        #pragma unroll
        for (int r = 0; r < 4; ++r)
            op[(size_t)(tg * 64 + tf * 16 + q * 4 + r) * 128] = C[tf][r];
}

// ---------------------------------------------------------------------------
extern "C" void kernel_launch(void* const* d_in, const int* in_sizes, int n_in,
                              void* d_out, int out_size, void* d_ws, size_t ws_size,
                              hipStream_t stream)
{
    const float* x    = (const float*)d_in[0];   // (4,4096,128)
    const float* keys = (const float*)d_in[1];   // (64,128)
    const float* ops  = (const float*)d_in[2];   // (64,128,128)
    const float* Wq   = (const float*)d_in[3];   // (128,128)
    const float* bq   = (const float*)d_in[4];   // (128,)
    float* out = (float*)d_out;

    (void)d_ws; (void)ws_size;   // no workspace: single self-sufficient dispatch
    fused_kernel<<<256, 512, 0, stream>>>(x, keys, ops, Wq, bq, out);
}